// Round 7
// baseline (113.358 us; speedup 1.0000x reference)
//
#include <hip/hip_runtime.h>
#include <hip/hip_bf16.h>
#include <cstdint>

#define NHEAD 8
#define HD 32
#define DM 256
#define HH 56
#define WWID 56
#define HW 3136          // 56*56
#define NB 2
#define NTOT (NB * HW)   // 6272 positions total (batch folded into N)
#define SCALE 0.17677669529663687f   // 32^-0.5

typedef _Float16 f16;
typedef __attribute__((ext_vector_type(2))) _Float16 f16x2;
typedef __attribute__((ext_vector_type(8))) _Float16 f16x8;   // 4 VGPRs
typedef __attribute__((ext_vector_type(4))) float floatx4;

union U16 { uint4 u; f16x2 h2[4]; f16 h[8]; };

// ---------------------------------------------------------------------------
// prep: fused x-transpose + weight convert. Block-uniform branch.
// bid < 392: transpose x [b][c][p] fp32 -> xT [b][p][c] f16, 64x64 tiles.
//   Stores are uint4 (8 f16) -> 128-B contiguous runs per 8 lanes (R6 used
//   scalar 2-B stores — 8x more store instrs at 2-B granularity).
// bid >= 392: wq/wk/wv -> wcat[768][256] f16, wo -> wob[256][256] f16.
// ---------------------------------------------------------------------------
__global__ __launch_bounds__(256) void prep(
    const float* __restrict__ x,
    const float* __restrict__ wq, const float* __restrict__ wk,
    const float* __restrict__ wv, const float* __restrict__ wo,
    f16* __restrict__ xT, f16* __restrict__ wcat, f16* __restrict__ wob)
{
    const int bid = blockIdx.x;
    const int t = threadIdx.x;
    if (bid < 392) {
        __shared__ float tile[64][65];
        const int b = bid / 196, r = bid - b * 196;   // 196 = 4 c-tiles * 49 p-tiles
        const int ct = r / 49, pt = r - ct * 49;
        const int p0 = pt * 64, c0 = ct * 64;
        const float* xb = x + (size_t)b * DM * HW;
        #pragma unroll
        for (int i = 0; i < 4; ++i) {                 // 1024 float4 loads
            const int u = t + i * 256;
            const int rc = u >> 4, p4 = (u & 15) << 2;
            *(float4*)&tile[rc][p4] =
                *(const float4*)&xb[(size_t)(c0 + rc) * HW + p0 + p4];
        }
        __syncthreads();
        f16* xo = xT + (size_t)b * HW * DM;
        #pragma unroll
        for (int i = 0; i < 2; ++i) {                 // 512 uint4 stores
            const int u = t + i * 256;
            const int ch = u & 7, p = u >> 3;         // ch: c-chunk, p: 0..63
            U16 pk;
            #pragma unroll
            for (int kk = 0; kk < 8; ++kk)            // stride-65 reads: conflict-free
                pk.h[kk] = (f16)tile[ch * 8 + kk][p];
            *(uint4*)&xo[(size_t)(p0 + p) * DM + c0 + ch * 8] = pk.u;
        }
    } else {
        const int gid = (bid - 392) * 256 + t;        // 65536 threads
        const int idx4 = gid << 2;
        const int sel = idx4 >> 16;                   // 0..3
        const int off = idx4 & 65535;
        const float* src = sel == 0 ? wq : (sel == 1 ? wk : (sel == 2 ? wv : wo));
        f16* dst = sel < 3 ? (wcat + (sel << 16) + off) : (wob + off);
        float4 f = *(const float4*)&src[off];
        union { ushort4 u; f16 h[4]; } pk;
        pk.h[0] = (f16)f.x; pk.h[1] = (f16)f.y;
        pk.h[2] = (f16)f.z; pk.h[3] = (f16)f.w;
        *(ushort4*)dst = pk.u;
    }
}

// ---------------------------------------------------------------------------
// MFMA GEMM, BK=64 (4 K-iters, 8 barriers vs R6's 16). Batch folded into N.
// A f16 [M][256] k-contig; B = xT/attnT [NTOT][256] k-contig.
// BM=128, BN=64, 4 waves, wave = 64x32 via 4x2 tiles of 16x16x32_f16.
// LDS rows padded to 72 f16 (144 B, 16B-aligned; frag b128 reads hit the
// 8-lane/4-bank-group minimum = conflict-free).
// MODE 0: M=768 fused qkv -> q/k/v f16 [b][h][p][d]; q pre-scaled by SCALE.
// MODE 1: M=256 out-proj  -> fp32 d_out [b][c][p].
// ---------------------------------------------------------------------------
template<int MODE>
__global__ __launch_bounds__(256) void gemm_mfma(
    const f16* __restrict__ A,
    const f16* __restrict__ Bm,
    const float* __restrict__ b0, const float* __restrict__ b1,
    const float* __restrict__ b2,
    void* __restrict__ o0, void* __restrict__ o1, void* __restrict__ o2)
{
    const int n0 = blockIdx.x * 64;       // global position tile (0..NTOT)
    const int m0 = blockIdx.y * 128;
    const int bb = n0 / HW;               // batch (tile never straddles: 3136%64==0)
    const int np = n0 - bb * HW;          // p0 within batch
    const f16* Bb = Bm + (size_t)n0 * DM;

    __shared__ __align__(16) f16 As[128][72];   // 18.4 KB
    __shared__ __align__(16) f16 Bs[64][72];    //  9.2 KB

    const int t = threadIdx.x;
    const int wave = t >> 6, lane = t & 63;
    const int quad = lane >> 4, l16 = lane & 15;
    const int mw = (wave & 1) * 64, nw = (wave >> 1) * 32;

    floatx4 acc[4][2] = {};

    const int srow = t >> 3, suc = (t & 7) << 3;   // staging map (16B chunks)

    for (int k0 = 0; k0 < DM; k0 += 64) {
        #pragma unroll
        for (int pp = 0; pp < 4; ++pp) {           // A: 1024 uint4
            const int row = srow + pp * 32;
            *(uint4*)&As[row][suc] =
                *(const uint4*)&A[(size_t)(m0 + row) * DM + k0 + suc];
        }
        #pragma unroll
        for (int pp = 0; pp < 2; ++pp) {           // B: 512 uint4
            const int row = srow + pp * 32;
            *(uint4*)&Bs[row][suc] =
                *(const uint4*)&Bb[(size_t)row * DM + k0 + suc];
        }
        __syncthreads();
        #pragma unroll
        for (int ks = 0; ks < 2; ++ks) {
            f16x8 af[4], bf[2];
            #pragma unroll
            for (int mt = 0; mt < 4; ++mt)
                af[mt] = *(const f16x8*)&As[mw + mt * 16 + l16][ks * 32 + quad * 8];
            #pragma unroll
            for (int nt = 0; nt < 2; ++nt)
                bf[nt] = *(const f16x8*)&Bs[nw + nt * 16 + l16][ks * 32 + quad * 8];
            #pragma unroll
            for (int mt = 0; mt < 4; ++mt)
                #pragma unroll
                for (int nt = 0; nt < 2; ++nt)
                    acc[mt][nt] = __builtin_amdgcn_mfma_f32_16x16x32_f16(
                        af[mt], bf[nt], acc[mt][nt], 0, 0, 0);
        }
        __syncthreads();
    }

    if (MODE == 0) {
        #pragma unroll
        for (int mt = 0; mt < 4; ++mt) {
            const int gm = m0 + mw + mt * 16 + quad * 4;
            const int proj = gm >> 8;
            const int c = gm & 255;
            const int h = c >> 5, d0 = c & 31;
            const float* bptr = proj == 0 ? b0 : (proj == 1 ? b1 : b2);
            f16* op = (f16*)(proj == 0 ? o0 : (proj == 1 ? o1 : o2));
            const float sc = proj == 0 ? SCALE : 1.0f;
            const size_t base = ((size_t)(bb * NHEAD + h) * HW) * HD + d0;
            float bias[4] = {bptr[c], bptr[c + 1], bptr[c + 2], bptr[c + 3]};
            #pragma unroll
            for (int nt = 0; nt < 2; ++nt) {
                const int p = np + nw + nt * 16 + l16;
                union { ushort4 u; f16 h[4]; } pk;
                #pragma unroll
                for (int r = 0; r < 4; ++r)
                    pk.h[r] = (f16)((acc[mt][nt][r] + bias[r]) * sc);
                *(ushort4*)&op[base + (size_t)p * HD] = pk.u;
            }
        }
    } else {
        float* yo = (float*)o0;
        #pragma unroll
        for (int mt = 0; mt < 4; ++mt) {
            const int gc = m0 + mw + mt * 16 + quad * 4;
            #pragma unroll
            for (int r = 0; r < 4; ++r) {
                const float bias = b0[gc + r];
                #pragma unroll
                for (int nt = 0; nt < 2; ++nt) {
                    const int p = np + nw + nt * 16 + l16;
                    yo[(size_t)(bb * DM + gc + r) * HW + p] = acc[mt][nt][r] + bias;
                }
            }
        }
    }
}

// ---------------------------------------------------------------------------
// Stage 2: sliding-window attention — unchanged from R6 (passing, no spills).
// d-split: 448 thr = 112 positions (2 rows x 56) x 4 chunk-lanes; ~40 VGPR
// live. f16: K score via v_dot2_f32_f16, V accum via fma_mix, q pre-scaled.
// LDS halo [pos'][chunk] uint4 -> wave reads contiguous 1KB, conflict-free.
// Zero-pad: y-OOB rows + guards zeroed; x-invalid adds exp(0)=1 to denom.
// ---------------------------------------------------------------------------
#define HROWS 8                    // 2 + 6 halo
#define HPOS  (HROWS * WWID)       // 448
#define HPP   (HPOS + 6)           // 454: +3 guard positions each side

__global__ __launch_bounds__(448) void attn_win(
    const f16* __restrict__ q,
    const f16* __restrict__ k,
    const f16* __restrict__ v,
    f16* __restrict__ out)
{
    __shared__ uint4 kh[HPP * 4];   // 29,056 B
    __shared__ uint4 vh[HPP * 4];   // 29,056 B

    const int t = threadIdx.x;            // 0..447
    const int tile = blockIdx.x;          // 0..27
    const int h = blockIdx.y, b = blockIdx.z;
    const int y0 = tile * 2;
    const size_t base = (size_t)(b * NHEAD + h) * HW * HD;
    const f16* kp = k + base;
    const f16* vp = v + base;

    #pragma unroll
    for (int it = 0; it < 4; ++it) {      // stage halo rows y0-3 .. y0+4
        const int u = t + it * 448;
        const int pos = u >> 2, ch = u & 3;
        const int hr = pos / WWID;
        const int gx = pos - hr * WWID;
        const int gy = y0 - 3 + hr;
        uint4 kv = make_uint4(0, 0, 0, 0), vv = make_uint4(0, 0, 0, 0);
        if ((unsigned)gy < HH) {
            const size_t g = (size_t)(gy * WWID + gx) * HD + (ch << 3);
            kv = *(const uint4*)&kp[g];
            vv = *(const uint4*)&vp[g];
        }
        kh[u + 12] = kv;
        vh[u + 12] = vv;
    }
    if (t < 48) {   // zero guards: 3 low + 3 high positions x 4 chunks
        const int ps = t % 6;
        const int fi = (ps < 3 ? ps * 4 : (HPOS + ps) * 4) + ((t / 6) & 3);
        const uint4 z = make_uint4(0, 0, 0, 0);
        if (t < 24) kh[fi] = z; else vh[fi] = z;
    }
    __syncthreads();

    const int pl = t >> 2;                // local position 0..111
    const int ch = t & 3;                 // chunk 0..3
    const int lx = pl >= WWID ? pl - WWID : pl;
    const int p = y0 * WWID + pl;

    U16 qu;                               // my q chunk (pre-scaled by SCALE)
    qu.u = *(const uint4*)(q + base + (size_t)p * HD + (ch << 3));

    const uint4* kb4 = kh + t;
    const uint4* vb4 = vh + t;

    float of[8] = {};
    float sum = 0.f;
    for (int i = 0; i < 7; ++i) {
        #pragma unroll
        for (int j = 0; j < 7; ++j) {
            const int off4 = (i * WWID + j) << 2;
            U16 ku; ku.u = kb4[off4];
            float s;
            s = __builtin_amdgcn_fdot2(ku.h2[0], qu.h2[0], 0.0f, false);
            s = __builtin_amdgcn_fdot2(ku.h2[1], qu.h2[1], s, false);
            s = __builtin_amdgcn_fdot2(ku.h2[2], qu.h2[2], s, false);
            s = __builtin_amdgcn_fdot2(ku.h2[3], qu.h2[3], s, false);
            s += __shfl_xor(s, 1);
            s += __shfl_xor(s, 2);
            const bool xv = (unsigned)(lx + j - 3) < WWID;
            const float e = __expf(s);
            sum += xv ? e : 1.0f;
            const float wt = xv ? e : 0.0f;
            U16 vu; vu.u = vb4[off4];
            of[0] = fmaf((float)vu.h[0], wt, of[0]);
            of[1] = fmaf((float)vu.h[1], wt, of[1]);
            of[2] = fmaf((float)vu.h[2], wt, of[2]);
            of[3] = fmaf((float)vu.h[3], wt, of[3]);
            of[4] = fmaf((float)vu.h[4], wt, of[4]);
            of[5] = fmaf((float)vu.h[5], wt, of[5]);
            of[6] = fmaf((float)vu.h[6], wt, of[6]);
            of[7] = fmaf((float)vu.h[7], wt, of[7]);
        }
    }

    const float inv = 1.0f / sum;
    f16* op = out + ((size_t)b * HW + p) * DM + h * HD + (ch << 3);
    U16 ou;
    #pragma unroll
    for (int j = 0; j < 8; ++j)
        ou.h[j] = (f16)(of[j] * inv);
    *(uint4*)op = ou.u;
}

// ---------------------------------------------------------------------------
extern "C" void kernel_launch(void* const* d_in, const int* in_sizes, int n_in,
                              void* d_out, int out_size, void* d_ws, size_t ws_size,
                              hipStream_t stream) {
    const float* x  = (const float*)d_in[0];
    const float* wq = (const float*)d_in[1];
    const float* bq = (const float*)d_in[2];
    const float* wk = (const float*)d_in[3];
    const float* bk = (const float*)d_in[4];
    const float* wv = (const float*)d_in[5];
    const float* bv = (const float*)d_in[6];
    const float* wo = (const float*)d_in[7];
    const float* bo = (const float*)d_in[8];
    float* out = (float*)d_out;

    const size_t NPC = (size_t)NTOT * DM;
    f16* xT    = (f16*)d_ws;               // [b][p][c]
    f16* wcat  = xT + NPC;                 // [768][256]
    f16* wob   = wcat + 768 * 256;         // [256][256]
    f16* qb    = wob + 256 * 256;          // [b][h][p][d], pre-scaled
    f16* kb    = qb + NPC;
    f16* vb    = kb + NPC;
    f16* attnT = vb + NPC;                 // [b][p][c]

    prep<<<648, 256, 0, stream>>>(x, wq, wk, wv, wo, xT, wcat, wob);
    gemm_mfma<0><<<dim3(NTOT / 64, 6), 256, 0, stream>>>(
        wcat, xT, bq, bk, bv, qb, kb, vb);
    attn_win<<<dim3(28, NHEAD, NB), 448, 0, stream>>>(qb, kb, vb, attnT);
    gemm_mfma<1><<<dim3(NTOT / 64, 2), 256, 0, stream>>>(
        wob, attnT, bo, bo, bo, out, out, out);
}